// Round 15
// baseline (192.207 us; speedup 1.0000x reference)
//
#include <hip/hip_runtime.h>

// Problem constants
#define NATOMS 20000
#define NCHAN  64
#define NIRR   16
#define K2 120
#define K1 8
#define K0 4

// ws layout (bytes):
//   [0 .. 524288)        W2bf  bf16[64][256][16]   c*4096 + xy*16 + i   (xy = x*16+y)
//   [524288 .. 557056)   W1bf  bf16[64][256]       TRANSPOSED: c*256 + y*16 + x
//   [557056 .. 561152)   W0f   f32 [64][16]        c*16 + x
#define W1_BYTE_OFF 524288
#define W0_BYTE_OFF 557056

#define NT 5               // tiles per wave (16 atoms each -> 80 atoms/block)

typedef __attribute__((ext_vector_type(8))) short bf16x8;
typedef __attribute__((ext_vector_type(4))) float f32x4;
typedef __attribute__((ext_vector_type(4))) unsigned int u32x4;

__device__ inline short f2bf(float f) {
    union { float f; unsigned u; } v; v.f = f;
    unsigned r = v.u + 0x7FFF + ((v.u >> 16) & 1);   // RNE
    return (short)(r >> 16);
}

// ---------------------------------------------------------------------------
// Kernel 1: fold weights (unchanged — tiled GEMM, W1 transposed, ~5 us).
// ---------------------------------------------------------------------------
__global__ __launch_bounds__(256) void precompute_kernel(
    const float* __restrict__ U2, const float* __restrict__ U1,
    const float* __restrict__ U0, const float* __restrict__ w2,
    const float* __restrict__ w1, const float* __restrict__ w0,
    void* __restrict__ wsv)
{
    short* W2bf = (short*)wsv;
    short* W1bf = (short*)((char*)wsv + W1_BYTE_OFF);
    float* W0f  = (float*)((char*)wsv + W0_BYTE_OFF);

    const int b = blockIdx.x;
    const int t = threadIdx.x;

    if (b < 256) {
        __shared__ __align__(16) float U2s[64][121];   // 30.9 KB
        __shared__ __align__(16) float w2s[120][16];   //  7.5 KB
        const int xyi0  = (b >> 2) * 64;
        const int cbase = (b & 3) * 16;

        for (int o = t; o < 64 * 120; o += 256) {
            int r = o / 120, k = o - r * 120;
            U2s[r][k] = U2[(size_t)xyi0 * 120 + o];
        }
        for (int o = t; o < 120 * 16; o += 256) {
            int k = o >> 4, cc = o & 15;
            w2s[k][cc] = w2[k * NCHAN + cbase + cc];
        }
        __syncthreads();

        const int r = t & 63;       // row (lane)
        const int g = t >> 6;       // wave = c sub-group of 4
        float acc0 = 0.f, acc1 = 0.f, acc2 = 0.f, acc3 = 0.f;
        #pragma unroll 8
        for (int k = 0; k < 120; ++k) {
            float u = U2s[r][k];                          // 2-way max, free
            float4 w = *(const float4*)&w2s[k][g * 4];    // wave-uniform broadcast
            acc0 += u * w.x; acc1 += u * w.y; acc2 += u * w.z; acc3 += u * w.w;
        }
        const int xyi = xyi0 + r;
        const int cA  = cbase + g * 4;
        W2bf[(size_t)(cA + 0) * 4096 + xyi] = f2bf(acc0);
        W2bf[(size_t)(cA + 1) * 4096 + xyi] = f2bf(acc1);
        W2bf[(size_t)(cA + 2) * 4096 + xyi] = f2bf(acc2);
        W2bf[(size_t)(cA + 3) * 4096 + xyi] = f2bf(acc3);
    } else {
        const int lb = b - 256;                // 0..7
        for (int o = t; o < 2048; o += 256) {
            int go = lb * 2048 + o;
            int c = go >> 8, xy = go & 255;    // xy = x*16 + i  (i == y)
            const float* u = U1 + xy * K1;
            float acc = 0.f;
            #pragma unroll
            for (int k = 0; k < K1; ++k) acc += u[k] * w1[k * NCHAN + c];
            // TRANSPOSED store: index = y*16 + x
            W1bf[c * 256 + ((xy & 15) << 4) + (xy >> 4)] = f2bf(acc);
        }
        if (lb == 0) {
            for (int o = t; o < 1024; o += 256) {
                int c = o >> 4, x = o & 15;
                const float* u = U0 + x * K0;
                float acc = 0.f;
                #pragma unroll
                for (int k = 0; k < K0; ++k) acc += u[k] * w0[k * NCHAN + c];
                W0f[c * 16 + x] = acc;
            }
        }
    }
}

// ---------------------------------------------------------------------------
// global -> LDS async copy, 16 B per lane (dest = wave-uniform base + lane*16)
// ---------------------------------------------------------------------------
__device__ __forceinline__ void gload_lds16(const void* g, void* l) {
    __builtin_amdgcn_global_load_lds(
        (const __attribute__((address_space(1))) unsigned int*)g,
        (__attribute__((address_space(3))) unsigned int*)l, 16, 0, 0);
}

// ---------------------------------------------------------------------------
// Per-tile math (verified MFMA structure; CHANGE vs R9: 8-deep accumulator
// rotation d0..d7 instead of 4-deep — 8 MFMAs in flight before the first
// dependent sy-FMA, halving the per-FMA wait on MFMA latency in the wave's
// in-order issue stream):
//   A[y][k]: k<16 -> W2bf[c][x*16+y][k]; k=16 -> bf16(C1[x,y]); else 0
//   B[k][a]: k<16 -> bf16(f[a][k]);      k=16 -> 1.0;           else 0
//   D[y][a] = M[x,y] (= A2 + C1);  lane (q,m) owns atom m, y-rows q*4..q*4+3.
//   s = sum_y f[y]*(sum_x f[x]*M[x,y] + C0[y]), reduced over q by 2 shfl_xor.
// ---------------------------------------------------------------------------
__device__ __forceinline__ float compute_tile(
    const bf16x8 (&aw)[16], float4 c0, int q,
    float4 va, float4 vb, float4 vc, float4 vd)
{
    float f0 = va.x, f1 = va.y, f2 = va.z, f3 = va.w;
    float f4 = vb.x, f5 = vb.y, f6 = vb.z, f7 = vb.w;
    float f8 = vc.x, f9 = vc.y, f10 = vc.z, f11 = vc.w;
    float f12 = vd.x, f13 = vd.y, f14 = vd.z, f15 = vd.w;

    unsigned pk0, pk1, pk2, pk3, pk4, pk5, pk6, pk7;
    asm("v_cvt_pk_bf16_f32 %0, %1, %2" : "=v"(pk0) : "v"(f0),  "v"(f1));
    asm("v_cvt_pk_bf16_f32 %0, %1, %2" : "=v"(pk1) : "v"(f2),  "v"(f3));
    asm("v_cvt_pk_bf16_f32 %0, %1, %2" : "=v"(pk2) : "v"(f4),  "v"(f5));
    asm("v_cvt_pk_bf16_f32 %0, %1, %2" : "=v"(pk3) : "v"(f6),  "v"(f7));
    asm("v_cvt_pk_bf16_f32 %0, %1, %2" : "=v"(pk4) : "v"(f8),  "v"(f9));
    asm("v_cvt_pk_bf16_f32 %0, %1, %2" : "=v"(pk5) : "v"(f10), "v"(f11));
    asm("v_cvt_pk_bf16_f32 %0, %1, %2" : "=v"(pk6) : "v"(f12), "v"(f13));
    asm("v_cvt_pk_bf16_f32 %0, %1, %2" : "=v"(pk7) : "v"(f14), "v"(f15));

    unsigned w0s = (q == 0) ? pk0 : (q == 1) ? pk4 : (q == 2) ? 0x00003f80u : 0u;
    unsigned w1s = (q == 0) ? pk1 : (q == 1) ? pk5 : 0u;
    unsigned w2s_ = (q == 0) ? pk2 : (q == 1) ? pk6 : 0u;
    unsigned w3s = (q == 0) ? pk3 : (q == 1) ? pk7 : 0u;
    u32x4 bu = {w0s, w1s, w2s_, w3s};
    bf16x8 bfr = __builtin_bit_cast(bf16x8, bu);

    const f32x4 z = {0.f, 0.f, 0.f, 0.f};
    f32x4 syA = z, syB = z;
    f32x4 d0 = __builtin_amdgcn_mfma_f32_16x16x32_bf16(aw[0], bfr, z, 0, 0, 0);
    f32x4 d1 = __builtin_amdgcn_mfma_f32_16x16x32_bf16(aw[1], bfr, z, 0, 0, 0);
    f32x4 d2 = __builtin_amdgcn_mfma_f32_16x16x32_bf16(aw[2], bfr, z, 0, 0, 0);
    f32x4 d3 = __builtin_amdgcn_mfma_f32_16x16x32_bf16(aw[3], bfr, z, 0, 0, 0);
    f32x4 d4 = __builtin_amdgcn_mfma_f32_16x16x32_bf16(aw[4], bfr, z, 0, 0, 0);
    f32x4 d5 = __builtin_amdgcn_mfma_f32_16x16x32_bf16(aw[5], bfr, z, 0, 0, 0);
    f32x4 d6 = __builtin_amdgcn_mfma_f32_16x16x32_bf16(aw[6], bfr, z, 0, 0, 0);
    f32x4 d7 = __builtin_amdgcn_mfma_f32_16x16x32_bf16(aw[7], bfr, z, 0, 0, 0);
    syA += d0 * f0;  d0 = __builtin_amdgcn_mfma_f32_16x16x32_bf16(aw[8],  bfr, z, 0, 0, 0);
    syB += d1 * f1;  d1 = __builtin_amdgcn_mfma_f32_16x16x32_bf16(aw[9],  bfr, z, 0, 0, 0);
    syA += d2 * f2;  d2 = __builtin_amdgcn_mfma_f32_16x16x32_bf16(aw[10], bfr, z, 0, 0, 0);
    syB += d3 * f3;  d3 = __builtin_amdgcn_mfma_f32_16x16x32_bf16(aw[11], bfr, z, 0, 0, 0);
    syA += d4 * f4;  d4 = __builtin_amdgcn_mfma_f32_16x16x32_bf16(aw[12], bfr, z, 0, 0, 0);
    syB += d5 * f5;  d5 = __builtin_amdgcn_mfma_f32_16x16x32_bf16(aw[13], bfr, z, 0, 0, 0);
    syA += d6 * f6;  d6 = __builtin_amdgcn_mfma_f32_16x16x32_bf16(aw[14], bfr, z, 0, 0, 0);
    syB += d7 * f7;  d7 = __builtin_amdgcn_mfma_f32_16x16x32_bf16(aw[15], bfr, z, 0, 0, 0);
    syA += d0 * f8;  syB += d1 * f9;  syA += d2 * f10; syB += d3 * f11;
    syA += d4 * f12; syB += d5 * f13; syA += d6 * f14; syB += d7 * f15;
    f32x4 sy = syA + syB;

    float t0 = (q & 1) ? f4 : f0;   float u0 = (q & 1) ? f12 : f8;
    float fy0 = (q & 2) ? u0 : t0;
    float t1 = (q & 1) ? f5 : f1;   float u1 = (q & 1) ? f13 : f9;
    float fy1 = (q & 2) ? u1 : t1;
    float t2 = (q & 1) ? f6 : f2;   float u2 = (q & 1) ? f14 : f10;
    float fy2 = (q & 2) ? u2 : t2;
    float t3 = (q & 1) ? f7 : f3;   float u3 = (q & 1) ? f15 : f11;
    float fy3 = (q & 2) ? u3 : t3;

    float s = fy0 * (sy.x + c0.x);
    s = fmaf(fy1, sy.y + c0.y, s);
    s = fmaf(fy2, sy.z + c0.z, s);
    s = fmaf(fy3, sy.w + c0.w, s);
    s += __shfl_xor(s, 16);
    s += __shfl_xor(s, 32);
    return s;
}

// ---------------------------------------------------------------------------
// Kernel 2: fused contraction — R9 shell verbatim (measured best: total
// 149.8 us, contract ~44 us).  Barrier-free per-wave streaming, single
// overlapped latency window: weights (19 VMEM) -> 5 stage gload_lds ->
// counted vmcnt(4-T) per tile.  Wave-private LDS, zero block barriers.
// ONLY change vs R9: compute_tile's 8-deep accumulator rotation (above).
// ---------------------------------------------------------------------------
__global__ __launch_bounds__(512, 4) void contract_kernel(
    const float* __restrict__ nf,   // [N, 64, 16]
    const void* __restrict__ wsv,
    float* __restrict__ out)        // [N, 64]
{
    __shared__ __align__(16) char fs[8][NT][1024];   // 40 KB, wave-private rows

    const short* W2g = (const short*)wsv;
    const short* W1g = (const short*)((const char*)wsv + W1_BYTE_OFF);
    const float* W0g = (const float*)((const char*)wsv + W0_BYTE_OFF);

    const int tid  = threadIdx.x;
    const int wave = tid >> 6;      // 0..7 = channel-within-group
    const int lane = tid & 63;
    const int m    = lane & 15;     // atom-within-tile
    const int q    = lane >> 4;
    const int c    = blockIdx.x * 8 + wave;
    const int atom0 = blockIdx.y * 80;   // chunk of 80 atoms, shared by waves

    // --- staging addresses: lane stages 16 B of atom a_st, slot r_st ---
    const int a_st = lane >> 2;                      // 0..15
    const int r_st = lane & 3;                       // LDS slot within 64-B row
    const int srcj = (r_st - (a_st >> 2)) & 3;       // inverse swizzle (bijective)
    const char* sbase = (const char*)nf
        + ((size_t)(atom0 + a_st) << 12)             // atom * 4096 B
        + (c << 6)                                   // channel * 64 B
        + (srcj << 4);
    char* ldst = &fs[wave][0][0];                    // wave-uniform dest

    // --- issue weight loads FIRST (19 VMEM, stay in flight) ---
    bf16x8 aw[16];
    #pragma unroll
    for (int j = 0; j < 16; ++j) aw[j] = (bf16x8)0;
    if (q < 2) {
        #pragma unroll
        for (int j = 0; j < 16; ++j)
            aw[j] = *(const bf16x8*)(W2g + ((size_t)c << 12) + ((j * 16 + m) << 4) + (q << 3));
    } else if (q == 2) {
        // 16 consecutive bf16 C1[x=0..15][y=m] (transposed layout): 2 dwordx4
        const uint4* wp = (const uint4*)(W1g + (c << 8) + (m << 4));
        uint4 wa = wp[0], wb = wp[1];
        unsigned t8[8] = {wa.x, wa.y, wa.z, wa.w, wb.x, wb.y, wb.z, wb.w};
        #pragma unroll
        for (int j = 0; j < 16; ++j) {
            unsigned w = (j & 1) ? (t8[j >> 1] >> 16) : (t8[j >> 1] & 0xffffu);
            bf16x8 v = (bf16x8)0;
            v[0] = (short)w;                 // k=16 slot
            aw[j] = v;
        }
    }
    const float4 c0 = *(const float4*)(W0g + (c << 4) + (q << 2));
    __builtin_amdgcn_sched_barrier(0);   // pin: weights issued before stages

    // --- issue all NT tile stages (overlap with weight latency) ---
    #pragma unroll
    for (int t = 0; t < NT; ++t)
        gload_lds16(sbase + (size_t)t * 65536, ldst + t * 1024);
    __builtin_amdgcn_sched_barrier(0);

    float outv[NT];

    #pragma unroll
    for (int T = 0; T < NT; ++T) {
        // in-order vmcnt: <=4-T outstanding => weights + stages 0..T complete
        if      (T == 0) asm volatile("s_waitcnt vmcnt(4)" ::: "memory");
        else if (T == 1) asm volatile("s_waitcnt vmcnt(3)" ::: "memory");
        else if (T == 2) asm volatile("s_waitcnt vmcnt(2)" ::: "memory");
        else if (T == 3) asm volatile("s_waitcnt vmcnt(1)" ::: "memory");
        else             asm volatile("s_waitcnt vmcnt(0)" ::: "memory");
        __builtin_amdgcn_sched_barrier(0);

        const char* lrb = &fs[wave][T][0] + (m << 6);
        float4 va = *(const float4*)(lrb + ((((0 + (m >> 2)) & 3)) << 4));
        float4 vb = *(const float4*)(lrb + ((((1 + (m >> 2)) & 3)) << 4));
        float4 vc = *(const float4*)(lrb + ((((2 + (m >> 2)) & 3)) << 4));
        float4 vd = *(const float4*)(lrb + ((((3 + (m >> 2)) & 3)) << 4));

        outv[T] = compute_tile(aw, c0, q, va, vb, vc, vd);
    }

    if (q == 0) {
        float* ob = out + ((size_t)(atom0 + m)) * 64 + c;
        #pragma unroll
        for (int T = 0; T < NT; ++T)
            ob[(size_t)T * 1024] = outv[T];   // atom += 16 -> +1024 floats
    }
}

extern "C" void kernel_launch(void* const* d_in, const int* in_sizes, int n_in,
                              void* d_out, int out_size, void* d_ws, size_t ws_size,
                              hipStream_t stream)
{
    const float* nf = (const float*)d_in[0];
    const float* U2 = (const float*)d_in[1];
    const float* U1 = (const float*)d_in[2];
    const float* U0 = (const float*)d_in[3];
    const float* w2 = (const float*)d_in[4];
    const float* w1 = (const float*)d_in[5];
    const float* w0 = (const float*)d_in[6];
    float* out = (float*)d_out;

    precompute_kernel<<<264, 256, 0, stream>>>(U2, U1, U0, w2, w1, w0, d_ws);

    dim3 grid(8, 250);   // x = channel group of 8, y = atom chunk of 80
    contract_kernel<<<grid, 512, 0, stream>>>(nf, d_ws, out);
}

// Round 17
// 149.808 us; speedup vs baseline: 1.2830x; 1.2830x over previous
//
#include <hip/hip_runtime.h>

// Problem constants
#define NATOMS 20000
#define NCHAN  64
#define NIRR   16
#define K2 120
#define K1 8
#define K0 4

// ws layout (bytes):
//   [0 .. 524288)        W2bf  bf16[64][256][16]   c*4096 + xy*16 + i   (xy = x*16+y)
//   [524288 .. 557056)   W1bf  bf16[64][256]       TRANSPOSED: c*256 + y*16 + x
//   [557056 .. 561152)   W0f   f32 [64][16]        c*16 + x
#define W1_BYTE_OFF 524288
#define W0_BYTE_OFF 557056

#define NT 5               // tiles per wave (16 atoms each -> 80 atoms/block)

typedef __attribute__((ext_vector_type(8))) short bf16x8;
typedef __attribute__((ext_vector_type(4))) float f32x4;
typedef __attribute__((ext_vector_type(4))) unsigned int u32x4;

__device__ inline short f2bf(float f) {
    union { float f; unsigned u; } v; v.f = f;
    unsigned r = v.u + 0x7FFF + ((v.u >> 16) & 1);   // RNE
    return (short)(r >> 16);
}

// ---------------------------------------------------------------------------
// Kernel 1: fold weights (tiled GEMM, W1 transposed, ~5 us).
// ---------------------------------------------------------------------------
__global__ __launch_bounds__(256) void precompute_kernel(
    const float* __restrict__ U2, const float* __restrict__ U1,
    const float* __restrict__ U0, const float* __restrict__ w2,
    const float* __restrict__ w1, const float* __restrict__ w0,
    void* __restrict__ wsv)
{
    short* W2bf = (short*)wsv;
    short* W1bf = (short*)((char*)wsv + W1_BYTE_OFF);
    float* W0f  = (float*)((char*)wsv + W0_BYTE_OFF);

    const int b = blockIdx.x;
    const int t = threadIdx.x;

    if (b < 256) {
        __shared__ __align__(16) float U2s[64][121];   // 30.9 KB
        __shared__ __align__(16) float w2s[120][16];   //  7.5 KB
        const int xyi0  = (b >> 2) * 64;
        const int cbase = (b & 3) * 16;

        for (int o = t; o < 64 * 120; o += 256) {
            int r = o / 120, k = o - r * 120;
            U2s[r][k] = U2[(size_t)xyi0 * 120 + o];
        }
        for (int o = t; o < 120 * 16; o += 256) {
            int k = o >> 4, cc = o & 15;
            w2s[k][cc] = w2[k * NCHAN + cbase + cc];
        }
        __syncthreads();

        const int r = t & 63;       // row (lane)
        const int g = t >> 6;       // wave = c sub-group of 4
        float acc0 = 0.f, acc1 = 0.f, acc2 = 0.f, acc3 = 0.f;
        #pragma unroll 8
        for (int k = 0; k < 120; ++k) {
            float u = U2s[r][k];                          // 2-way max, free
            float4 w = *(const float4*)&w2s[k][g * 4];    // wave-uniform broadcast
            acc0 += u * w.x; acc1 += u * w.y; acc2 += u * w.z; acc3 += u * w.w;
        }
        const int xyi = xyi0 + r;
        const int cA  = cbase + g * 4;
        W2bf[(size_t)(cA + 0) * 4096 + xyi] = f2bf(acc0);
        W2bf[(size_t)(cA + 1) * 4096 + xyi] = f2bf(acc1);
        W2bf[(size_t)(cA + 2) * 4096 + xyi] = f2bf(acc2);
        W2bf[(size_t)(cA + 3) * 4096 + xyi] = f2bf(acc3);
    } else {
        const int lb = b - 256;                // 0..7
        for (int o = t; o < 2048; o += 256) {
            int go = lb * 2048 + o;
            int c = go >> 8, xy = go & 255;    // xy = x*16 + i  (i == y)
            const float* u = U1 + xy * K1;
            float acc = 0.f;
            #pragma unroll
            for (int k = 0; k < K1; ++k) acc += u[k] * w1[k * NCHAN + c];
            // TRANSPOSED store: index = y*16 + x
            W1bf[c * 256 + ((xy & 15) << 4) + (xy >> 4)] = f2bf(acc);
        }
        if (lb == 0) {
            for (int o = t; o < 1024; o += 256) {
                int c = o >> 4, x = o & 15;
                const float* u = U0 + x * K0;
                float acc = 0.f;
                #pragma unroll
                for (int k = 0; k < K0; ++k) acc += u[k] * w0[k * NCHAN + c];
                W0f[c * 16 + x] = acc;
            }
        }
    }
}

// ---------------------------------------------------------------------------
// global -> LDS async copy, 16 B per lane (dest = wave-uniform base + lane*16)
// ---------------------------------------------------------------------------
__device__ __forceinline__ void gload_lds16(const void* g, void* l) {
    __builtin_amdgcn_global_load_lds(
        (const __attribute__((address_space(1))) unsigned int*)g,
        (__attribute__((address_space(3))) unsigned int*)l, 16, 0, 0);
}

// ---------------------------------------------------------------------------
// Per-tile math (verified MFMA structure; R9 4-deep rotation — measured
// best.  R15's 8-deep variant spilled to scratch (WRITE 9->136 MB) and
// regressed 44->88 us: the register file is exactly full at 4-deep.
//   A[y][k]: k<16 -> W2bf[c][x*16+y][k]; k=16 -> bf16(C1[x,y]); else 0
//   B[k][a]: k<16 -> bf16(f[a][k]);      k=16 -> 1.0;           else 0
//   D[y][a] = M[x,y] (= A2 + C1);  lane (q,m) owns atom m, y-rows q*4..q*4+3.
//   s = sum_y f[y]*(sum_x f[x]*M[x,y] + C0[y]), reduced over q by 2 shfl_xor.
// ---------------------------------------------------------------------------
__device__ __forceinline__ float compute_tile(
    const bf16x8 (&aw)[16], float4 c0, int q,
    float4 va, float4 vb, float4 vc, float4 vd)
{
    float f0 = va.x, f1 = va.y, f2 = va.z, f3 = va.w;
    float f4 = vb.x, f5 = vb.y, f6 = vb.z, f7 = vb.w;
    float f8 = vc.x, f9 = vc.y, f10 = vc.z, f11 = vc.w;
    float f12 = vd.x, f13 = vd.y, f14 = vd.z, f15 = vd.w;

    unsigned pk0, pk1, pk2, pk3, pk4, pk5, pk6, pk7;
    asm("v_cvt_pk_bf16_f32 %0, %1, %2" : "=v"(pk0) : "v"(f0),  "v"(f1));
    asm("v_cvt_pk_bf16_f32 %0, %1, %2" : "=v"(pk1) : "v"(f2),  "v"(f3));
    asm("v_cvt_pk_bf16_f32 %0, %1, %2" : "=v"(pk2) : "v"(f4),  "v"(f5));
    asm("v_cvt_pk_bf16_f32 %0, %1, %2" : "=v"(pk3) : "v"(f6),  "v"(f7));
    asm("v_cvt_pk_bf16_f32 %0, %1, %2" : "=v"(pk4) : "v"(f8),  "v"(f9));
    asm("v_cvt_pk_bf16_f32 %0, %1, %2" : "=v"(pk5) : "v"(f10), "v"(f11));
    asm("v_cvt_pk_bf16_f32 %0, %1, %2" : "=v"(pk6) : "v"(f12), "v"(f13));
    asm("v_cvt_pk_bf16_f32 %0, %1, %2" : "=v"(pk7) : "v"(f14), "v"(f15));

    unsigned w0s = (q == 0) ? pk0 : (q == 1) ? pk4 : (q == 2) ? 0x00003f80u : 0u;
    unsigned w1s = (q == 0) ? pk1 : (q == 1) ? pk5 : 0u;
    unsigned w2s_ = (q == 0) ? pk2 : (q == 1) ? pk6 : 0u;
    unsigned w3s = (q == 0) ? pk3 : (q == 1) ? pk7 : 0u;
    u32x4 bu = {w0s, w1s, w2s_, w3s};
    bf16x8 bfr = __builtin_bit_cast(bf16x8, bu);

    const f32x4 z = {0.f, 0.f, 0.f, 0.f};
    f32x4 syA = z, syB = z;
    f32x4 d0 = __builtin_amdgcn_mfma_f32_16x16x32_bf16(aw[0], bfr, z, 0, 0, 0);
    f32x4 d1 = __builtin_amdgcn_mfma_f32_16x16x32_bf16(aw[1], bfr, z, 0, 0, 0);
    f32x4 d2 = __builtin_amdgcn_mfma_f32_16x16x32_bf16(aw[2], bfr, z, 0, 0, 0);
    f32x4 d3 = __builtin_amdgcn_mfma_f32_16x16x32_bf16(aw[3], bfr, z, 0, 0, 0);
    syA += d0 * f0;  d0 = __builtin_amdgcn_mfma_f32_16x16x32_bf16(aw[4],  bfr, z, 0, 0, 0);
    syB += d1 * f1;  d1 = __builtin_amdgcn_mfma_f32_16x16x32_bf16(aw[5],  bfr, z, 0, 0, 0);
    syA += d2 * f2;  d2 = __builtin_amdgcn_mfma_f32_16x16x32_bf16(aw[6],  bfr, z, 0, 0, 0);
    syB += d3 * f3;  d3 = __builtin_amdgcn_mfma_f32_16x16x32_bf16(aw[7],  bfr, z, 0, 0, 0);
    syA += d0 * f4;  d0 = __builtin_amdgcn_mfma_f32_16x16x32_bf16(aw[8],  bfr, z, 0, 0, 0);
    syB += d1 * f5;  d1 = __builtin_amdgcn_mfma_f32_16x16x32_bf16(aw[9],  bfr, z, 0, 0, 0);
    syA += d2 * f6;  d2 = __builtin_amdgcn_mfma_f32_16x16x32_bf16(aw[10], bfr, z, 0, 0, 0);
    syB += d3 * f7;  d3 = __builtin_amdgcn_mfma_f32_16x16x32_bf16(aw[11], bfr, z, 0, 0, 0);
    syA += d0 * f8;  d0 = __builtin_amdgcn_mfma_f32_16x16x32_bf16(aw[12], bfr, z, 0, 0, 0);
    syB += d1 * f9;  d1 = __builtin_amdgcn_mfma_f32_16x16x32_bf16(aw[13], bfr, z, 0, 0, 0);
    syA += d2 * f10; d2 = __builtin_amdgcn_mfma_f32_16x16x32_bf16(aw[14], bfr, z, 0, 0, 0);
    syB += d3 * f11; d3 = __builtin_amdgcn_mfma_f32_16x16x32_bf16(aw[15], bfr, z, 0, 0, 0);
    syA += d0 * f12; syB += d1 * f13; syA += d2 * f14; syB += d3 * f15;
    f32x4 sy = syA + syB;

    float t0 = (q & 1) ? f4 : f0;   float u0 = (q & 1) ? f12 : f8;
    float fy0 = (q & 2) ? u0 : t0;
    float t1 = (q & 1) ? f5 : f1;   float u1 = (q & 1) ? f13 : f9;
    float fy1 = (q & 2) ? u1 : t1;
    float t2 = (q & 1) ? f6 : f2;   float u2 = (q & 1) ? f14 : f10;
    float fy2 = (q & 2) ? u2 : t2;
    float t3 = (q & 1) ? f7 : f3;   float u3 = (q & 1) ? f15 : f11;
    float fy3 = (q & 2) ? u3 : t3;

    float s = fy0 * (sy.x + c0.x);
    s = fmaf(fy1, sy.y + c0.y, s);
    s = fmaf(fy2, sy.z + c0.z, s);
    s = fmaf(fy3, sy.w + c0.w, s);
    s += __shfl_xor(s, 16);
    s += __shfl_xor(s, 32);
    return s;
}

// ---------------------------------------------------------------------------
// Kernel 2: fused contraction — R9 verbatim (measured best: total 149.8 us,
// contract ~44 us).  Barrier-free per-wave streaming, single overlapped
// latency window: weights (19 VMEM) -> 5 stage gload_lds -> counted
// vmcnt(4-T) per tile.  Wave-private LDS slices, zero block barriers.
// Measured family ranking: streaming-NT5 44 < depth-3-barriers 56 <
// bulk 61 < ring-NT10 64 < 8-deep-ILP(spill) 88 us.
// ---------------------------------------------------------------------------
__global__ __launch_bounds__(512, 4) void contract_kernel(
    const float* __restrict__ nf,   // [N, 64, 16]
    const void* __restrict__ wsv,
    float* __restrict__ out)        // [N, 64]
{
    __shared__ __align__(16) char fs[8][NT][1024];   // 40 KB, wave-private rows

    const short* W2g = (const short*)wsv;
    const short* W1g = (const short*)((const char*)wsv + W1_BYTE_OFF);
    const float* W0g = (const float*)((const char*)wsv + W0_BYTE_OFF);

    const int tid  = threadIdx.x;
    const int wave = tid >> 6;      // 0..7 = channel-within-group
    const int lane = tid & 63;
    const int m    = lane & 15;     // atom-within-tile
    const int q    = lane >> 4;
    const int c    = blockIdx.x * 8 + wave;
    const int atom0 = blockIdx.y * 80;   // chunk of 80 atoms, shared by waves

    // --- staging addresses: lane stages 16 B of atom a_st, slot r_st ---
    const int a_st = lane >> 2;                      // 0..15
    const int r_st = lane & 3;                       // LDS slot within 64-B row
    const int srcj = (r_st - (a_st >> 2)) & 3;       // inverse swizzle (bijective)
    const char* sbase = (const char*)nf
        + ((size_t)(atom0 + a_st) << 12)             // atom * 4096 B
        + (c << 6)                                   // channel * 64 B
        + (srcj << 4);
    char* ldst = &fs[wave][0][0];                    // wave-uniform dest

    // --- issue weight loads FIRST (19 VMEM, stay in flight) ---
    bf16x8 aw[16];
    #pragma unroll
    for (int j = 0; j < 16; ++j) aw[j] = (bf16x8)0;
    if (q < 2) {
        #pragma unroll
        for (int j = 0; j < 16; ++j)
            aw[j] = *(const bf16x8*)(W2g + ((size_t)c << 12) + ((j * 16 + m) << 4) + (q << 3));
    } else if (q == 2) {
        // 16 consecutive bf16 C1[x=0..15][y=m] (transposed layout): 2 dwordx4
        const uint4* wp = (const uint4*)(W1g + (c << 8) + (m << 4));
        uint4 wa = wp[0], wb = wp[1];
        unsigned t8[8] = {wa.x, wa.y, wa.z, wa.w, wb.x, wb.y, wb.z, wb.w};
        #pragma unroll
        for (int j = 0; j < 16; ++j) {
            unsigned w = (j & 1) ? (t8[j >> 1] >> 16) : (t8[j >> 1] & 0xffffu);
            bf16x8 v = (bf16x8)0;
            v[0] = (short)w;                 // k=16 slot
            aw[j] = v;
        }
    }
    const float4 c0 = *(const float4*)(W0g + (c << 4) + (q << 2));
    __builtin_amdgcn_sched_barrier(0);   // pin: weights issued before stages

    // --- issue all NT tile stages (overlap with weight latency) ---
    #pragma unroll
    for (int t = 0; t < NT; ++t)
        gload_lds16(sbase + (size_t)t * 65536, ldst + t * 1024);
    __builtin_amdgcn_sched_barrier(0);

    float outv[NT];

    #pragma unroll
    for (int T = 0; T < NT; ++T) {
        // in-order vmcnt: <=4-T outstanding => weights + stages 0..T complete
        if      (T == 0) asm volatile("s_waitcnt vmcnt(4)" ::: "memory");
        else if (T == 1) asm volatile("s_waitcnt vmcnt(3)" ::: "memory");
        else if (T == 2) asm volatile("s_waitcnt vmcnt(2)" ::: "memory");
        else if (T == 3) asm volatile("s_waitcnt vmcnt(1)" ::: "memory");
        else             asm volatile("s_waitcnt vmcnt(0)" ::: "memory");
        __builtin_amdgcn_sched_barrier(0);

        const char* lrb = &fs[wave][T][0] + (m << 6);
        float4 va = *(const float4*)(lrb + ((((0 + (m >> 2)) & 3)) << 4));
        float4 vb = *(const float4*)(lrb + ((((1 + (m >> 2)) & 3)) << 4));
        float4 vc = *(const float4*)(lrb + ((((2 + (m >> 2)) & 3)) << 4));
        float4 vd = *(const float4*)(lrb + ((((3 + (m >> 2)) & 3)) << 4));

        outv[T] = compute_tile(aw, c0, q, va, vb, vc, vd);
    }

    if (q == 0) {
        float* ob = out + ((size_t)(atom0 + m)) * 64 + c;
        #pragma unroll
        for (int T = 0; T < NT; ++T)
            ob[(size_t)T * 1024] = outv[T];   // atom += 16 -> +1024 floats
    }
}

extern "C" void kernel_launch(void* const* d_in, const int* in_sizes, int n_in,
                              void* d_out, int out_size, void* d_ws, size_t ws_size,
                              hipStream_t stream)
{
    const float* nf = (const float*)d_in[0];
    const float* U2 = (const float*)d_in[1];
    const float* U1 = (const float*)d_in[2];
    const float* U0 = (const float*)d_in[3];
    const float* w2 = (const float*)d_in[4];
    const float* w1 = (const float*)d_in[5];
    const float* w0 = (const float*)d_in[6];
    float* out = (float*)d_out;

    precompute_kernel<<<264, 256, 0, stream>>>(U2, U1, U0, w2, w1, w0, d_ws);

    dim3 grid(8, 250);   // x = channel group of 8, y = atom chunk of 80
    contract_kernel<<<grid, 512, 0, stream>>>(nf, d_ws, out);
}